// Round 5
// baseline (349.443 us; speedup 1.0000x reference)
//
#include <hip/hip_runtime.h>
#include <math.h>

#define Bb 64
#define Nn 512
#define Ff 64
#define Dd 64
#define Kk 20
#define Hh 32
#define ROWS (Bb*Nn)   /* 32768 */
#define EPSc 1e-5f
#define NEG 0.2f

// workspace (float units):
// 512    : topk_idx[512*20] (int)
// 10752  : stats[512]: gsum1[64] gsq1[64] gsum2[64] gsq2[64]
// 11264  : a_i[32768]
// 44032  : a_j[32768]
// 76800  : xw[32768*64]
// 2173952: gout/y [32768*64]

__device__ __forceinline__ float dot4(float4 a, float4 b) {
    return a.x*b.x + a.y*b.y + a.z*b.z + a.w*b.w;
}
__device__ __forceinline__ void xr4(float4& a, int m) {
    a.x += __shfl_xor(a.x, m); a.y += __shfl_xor(a.y, m);
    a.z += __shfl_xor(a.z, m); a.w += __shfl_xor(a.w, m);
}

// ---------- Launch 1: topk (blocks 0..511) || xw + a_i/a_j (blocks 512..1023)
__global__ __launch_bounds__(256) void k_p1(const float* __restrict__ data,
                                            const float* __restrict__ emb,
                                            const float* __restrict__ Wg,
                                            const float* __restrict__ att_i,
                                            const float* __restrict__ att_j,
                                            const float* __restrict__ att_em_i,
                                            const float* __restrict__ att_em_j,
                                            int* __restrict__ topk,
                                            float* __restrict__ stats,
                                            float* __restrict__ ai,
                                            float* __restrict__ aj,
                                            float* __restrict__ xw) {
    __shared__ __align__(16) float shbuf[576];   // topk: wish[64]+sv[512]; xw: sh[256]
    int t = threadIdx.x, blk = blockIdx.x;
    if (blk < Nn) {
        float* wish = shbuf;
        float* sv   = shbuf + 64;
        int i = blk;
        if (t < 64) {
            float wv = emb[i*64 + t];
            float ss = wv*wv;
            #pragma unroll
            for (int s = 32; s > 0; s >>= 1) ss += __shfl_xor(ss, s);
            wish[t] = wv * (1.f / sqrtf(ss));
        }
        __syncthreads();
        int seg = t & 3, jl = t >> 2;
        const float4* wish4 = (const float4*)wish;
        float4 wn[4];
        #pragma unroll
        for (int q = 0; q < 4; q++) wn[q] = wish4[seg*4 + q];
        const float4* emb4 = (const float4*)emb;
        for (int jb = 0; jb < 8; jb++) {
            int j = jb*64 + jl;
            float p = 0.f, s2 = 0.f;
            #pragma unroll
            for (int q = 0; q < 4; q++) {
                float4 e = emb4[j*16 + seg*4 + q];
                p += dot4(e, wn[q]); s2 += dot4(e, e);
            }
            p  += __shfl_xor(p, 1);  p  += __shfl_xor(p, 2);
            s2 += __shfl_xor(s2, 1); s2 += __shfl_xor(s2, 2);
            if (seg == 0) sv[j] = p * (1.f / sqrtf(s2));
        }
        __syncthreads();
        if (t < 64) {
            float v[8];
            #pragma unroll
            for (int q = 0; q < 8; q++) v[q] = sv[q*64 + t];
            for (int k = 0; k < Kk; k++) {
                float bv = v[0]; int bi = t;
                #pragma unroll
                for (int q = 1; q < 8; q++)
                    if (v[q] > bv) { bv = v[q]; bi = q*64 + t; }
                #pragma unroll
                for (int s = 1; s < 64; s <<= 1) {
                    float ov = __shfl_xor(bv, s); int oi = __shfl_xor(bi, s);
                    if (ov > bv || (ov == bv && oi < bi)) { bv = ov; bi = oi; }
                }
                if (t == 0) topk[i*Kk + k] = bi;
                #pragma unroll
                for (int q = 0; q < 8; q++)
                    if (bi == q*64 + t) v[q] = -INFINITY;
            }
        }
    } else {
        if (blk == Nn) stats[t] = 0.f;               // zero BN accumulators
        float* sh = shbuf;
        int xcd = blk & 7, sub2 = (blk - Nn) >> 3;   // 0..63
        int d = t & 63, r = t >> 6;
        const float4* wg4 = (const float4*)Wg;
        float4 w4[16];
        #pragma unroll
        for (int q = 0; q < 16; q++) w4[q] = wg4[d*16 + q];
        float atti = att_i[d], attj = att_j[d];
        float aemi = att_em_i[d], aemj = att_em_j[d];
        const float4* sh4 = (const float4*)sh;
        for (int it = 0; it < 16; it++) {
            int g = xcd*1024 + it*64 + sub2;
            sh[t] = data[g*256 + t];
            __syncthreads();
            float acc = 0.f;
            #pragma unroll
            for (int q = 0; q < 16; q++) acc += dot4(sh4[r*16 + q], w4[q]);
            int row = g*4 + r;
            xw[row*64 + d] = acc;
            int n = row & (Nn - 1);
            float wv = emb[n*64 + d];
            float vi = acc*atti + wv*aemi;
            float vj = acc*attj + wv*aemj;
            #pragma unroll
            for (int s = 32; s > 0; s >>= 1) { vi += __shfl_xor(vi, s); vj += __shfl_xor(vj, s); }
            if (d == 0) { ai[row] = vi; aj[row] = vj; }
            __syncthreads();
        }
    }
}

// ---------- Launch 2: attention gather + lane-parallel softmax + float4 PV + BN1 stats
__global__ __launch_bounds__(256) void k_gnn2(const float* __restrict__ xw,
                                              const float* __restrict__ ai,
                                              const float* __restrict__ aj,
                                              const int* __restrict__ topk,
                                              const float* __restrict__ bias,
                                              float* __restrict__ gout,
                                              float* __restrict__ stats) {
    __shared__ __align__(16) float4 s1[4][16], s2[4][16];
    int t = threadIdx.x;
    int xcd = blockIdx.x & 7, sub = blockIdx.x >> 3;   // sub 0..127
    int l = t & 63, w = t >> 6;
    int q = l & 15, kg = l >> 4, kk = l & 31;
    const float4* xw4 = (const float4*)xw;
    float4* gout4 = (float4*)gout;
    float4 bias4 = ((const float4*)bias)[q];
    float4 sum4 = {0,0,0,0}, sq4 = {0,0,0,0};
    for (int it = 0; it < 8; it++) {
        int g = xcd*1024 + it*128 + sub;
        int row = g*4 + w;
        int b = row >> 9, n = row & (Nn - 1);
        int base = b << 9;
        float aival = ai[row];
        int j = 0; float v = -1e30f;
        if (kk < Kk) {
            j = topk[n*Kk + kk];
            float x = aival + aj[base + j];
            v = x > 0.f ? x : NEG * x;
        }
        float m = v;
        #pragma unroll
        for (int s = 1; s <= 16; s <<= 1) m = fmaxf(m, __shfl_xor(m, s));
        float e = (kk < Kk) ? __expf(v - m) : 0.f;
        float es = e;
        #pragma unroll
        for (int s = 1; s <= 16; s <<= 1) es += __shfl_xor(es, s);
        float alpha = e * (1.f / es);
        float4 acc = {0,0,0,0};
        #pragma unroll
        for (int i = 0; i < 5; i++) {
            int k = i*4 + kg;                    // covers 0..19 across kg groups
            float ak = __shfl(alpha, k);
            int   jk = __shfl(j, k);
            float4 xv = xw4[(base + jk)*16 + q];
            acc.x += ak*xv.x; acc.y += ak*xv.y; acc.z += ak*xv.z; acc.w += ak*xv.w;
        }
        xr4(acc, 16); xr4(acc, 32);
        if (l < 16) {
            float4 r4;
            r4.x = acc.x + bias4.x; r4.y = acc.y + bias4.y;
            r4.z = acc.z + bias4.z; r4.w = acc.w + bias4.w;
            gout4[row*16 + q] = r4;
            sum4.x += r4.x; sum4.y += r4.y; sum4.z += r4.z; sum4.w += r4.w;
            sq4.x += r4.x*r4.x; sq4.y += r4.y*r4.y; sq4.z += r4.z*r4.z; sq4.w += r4.w*r4.w;
        }
    }
    if (l < 16) { s1[w][q] = sum4; s2[w][q] = sq4; }
    __syncthreads();
    if (t < 16) {
        float4 a = s1[0][t], c = s2[0][t];
        #pragma unroll
        for (int ww = 1; ww < 4; ww++) {
            float4 x1 = s1[ww][t], x2 = s2[ww][t];
            a.x += x1.x; a.y += x1.y; a.z += x1.z; a.w += x1.w;
            c.x += x2.x; c.y += x2.y; c.z += x2.z; c.w += x2.w;
        }
        atomicAdd(&stats[4*t+0], a.x); atomicAdd(&stats[4*t+1], a.y);
        atomicAdd(&stats[4*t+2], a.z); atomicAdd(&stats[4*t+3], a.w);
        atomicAdd(&stats[64+4*t+0], c.x); atomicAdd(&stats[64+4*t+1], c.y);
        atomicAdd(&stats[64+4*t+2], c.z); atomicAdd(&stats[64+4*t+3], c.w);
    }
}

// ---------- Launch 3: BN1 finalize (inline) + relu + *emb, BN2 stats
__global__ __launch_bounds__(256) void k_bn1(float* __restrict__ gout,
                                             const float* __restrict__ emb,
                                             const float* __restrict__ bn1_g,
                                             const float* __restrict__ bn1_b,
                                             float* __restrict__ stats) {
    __shared__ __align__(16) float4 s1[4][16], s2[4][16];
    int t = threadIdx.x;
    int xcd = blockIdx.x & 7, sub = blockIdx.x >> 3;
    int q = t & 15;
    float4 A4, C4;
    {
        float* Ap = &A4.x; float* Cp = &C4.x;
        #pragma unroll
        for (int c = 0; c < 4; c++) {
            int d = 4*q + c;
            float mean = stats[d] * (1.f/ROWS);
            float ex2  = stats[64+d] * (1.f/ROWS);
            float var  = ex2 - mean*mean;
            float A = (1.f / sqrtf(var + EPSc)) * bn1_g[d];
            Ap[c] = A; Cp[c] = bn1_b[d] - mean * A;
        }
    }
    float4* gout4 = (float4*)gout;
    const float4* emb4 = (const float4*)emb;
    float4 sum4 = {0,0,0,0}, sq4 = {0,0,0,0};
    #pragma unroll
    for (int i = 0; i < 2; i++) {
        int f = xcd*65536 + i*32768 + sub*256 + t;
        int row = f >> 4, n = row & (Nn - 1);
        float4 x = gout4[f];
        float4 wv = emb4[n*16 + q];
        float4 v;
        v.x = fmaxf(x.x*A4.x + C4.x, 0.f) * wv.x;
        v.y = fmaxf(x.y*A4.y + C4.y, 0.f) * wv.y;
        v.z = fmaxf(x.z*A4.z + C4.z, 0.f) * wv.z;
        v.w = fmaxf(x.w*A4.w + C4.w, 0.f) * wv.w;
        gout4[f] = v;
        sum4.x += v.x; sum4.y += v.y; sum4.z += v.z; sum4.w += v.w;
        sq4.x += v.x*v.x; sq4.y += v.y*v.y; sq4.z += v.z*v.z; sq4.w += v.w*v.w;
    }
    xr4(sum4, 16); xr4(sum4, 32);
    xr4(sq4, 16);  xr4(sq4, 32);
    int l = t & 63, w = t >> 6;
    if (l < 16) { s1[w][q] = sum4; s2[w][q] = sq4; }
    __syncthreads();
    if (t < 16) {
        float4 a = s1[0][t], c = s2[0][t];
        #pragma unroll
        for (int ww = 1; ww < 4; ww++) {
            float4 x1 = s1[ww][t], x2 = s2[ww][t];
            a.x += x1.x; a.y += x1.y; a.z += x1.z; a.w += x1.w;
            c.x += x2.x; c.y += x2.y; c.z += x2.z; c.w += x2.w;
        }
        atomicAdd(&stats[128+4*t+0], a.x); atomicAdd(&stats[128+4*t+1], a.y);
        atomicAdd(&stats[128+4*t+2], a.z); atomicAdd(&stats[128+4*t+3], a.w);
        atomicAdd(&stats[192+4*t+0], c.x); atomicAdd(&stats[192+4*t+1], c.y);
        atomicAdd(&stats[192+4*t+2], c.z); atomicAdd(&stats[192+4*t+3], c.w);
    }
}

// ---------- Launch 4: BN2 finalize (inline) + relu + lin(64->32) + out(32->64)
__global__ __launch_bounds__(256) void k_head2(const float* __restrict__ y,
                                               const float* __restrict__ stats,
                                               const float* __restrict__ bn2_g,
                                               const float* __restrict__ bn2_b,
                                               const float* __restrict__ linW,
                                               const float* __restrict__ linb,
                                               const float* __restrict__ outW,
                                               const float* __restrict__ outb,
                                               float* __restrict__ out) {
    __shared__ __align__(16) float zsh[4][64];
    __shared__ __align__(16) float hsh[4][32];
    int t = threadIdx.x;
    int d = t & 63, r = t >> 6;
    int j = d & 31, half = d >> 5;
    float mean = stats[128+d] * (1.f/ROWS);
    float ex2  = stats[192+d] * (1.f/ROWS);
    float var  = ex2 - mean*mean;
    float A = (1.f / sqrtf(var + EPSc)) * bn2_g[d];
    float C = bn2_b[d] - mean * A;
    const float4* linW4 = (const float4*)linW;
    const float4* outW4 = (const float4*)outW;
    float4 lw4[8], ow4[8];
    #pragma unroll
    for (int q = 0; q < 8; q++) lw4[q] = linW4[j*16 + half*8 + q];
    #pragma unroll
    for (int q = 0; q < 8; q++) ow4[q] = outW4[d*8 + q];
    float lb = linb[j], ob = outb[d];
    const float4* zsh4 = (const float4*)zsh;
    const float4* hsh4 = (const float4*)hsh;
    int xcd = blockIdx.x & 7, sub = blockIdx.x >> 3;
    for (int it = 0; it < 8; it++) {
        int g = xcd*1024 + it*128 + sub;
        int row = g*4 + r;
        float x = y[row*64 + d];
        float z = fmaxf(x*A + C, 0.f);
        zsh[r][d] = z;
        __syncthreads();
        float p = 0.f;
        #pragma unroll
        for (int q = 0; q < 8; q++) p += dot4(zsh4[r*16 + half*8 + q], lw4[q]);
        p += __shfl_xor(p, 32);
        if (half == 0) hsh[r][j] = p + lb;
        __syncthreads();
        float o = ob;
        #pragma unroll
        for (int q = 0; q < 8; q++) o += dot4(hsh4[r*8 + q], ow4[q]);
        out[row*64 + d] = o;
        __syncthreads();
    }
}

extern "C" void kernel_launch(void* const* d_in, const int* in_sizes, int n_in,
                              void* d_out, int out_size, void* d_ws, size_t ws_size,
                              hipStream_t stream) {
    const float* data     = (const float*)d_in[0];
    const float* emb      = (const float*)d_in[2];
    const float* Wg       = (const float*)d_in[3];
    const float* att_i    = (const float*)d_in[4];
    const float* att_j    = (const float*)d_in[5];
    const float* att_em_i = (const float*)d_in[6];
    const float* att_em_j = (const float*)d_in[7];
    const float* bias     = (const float*)d_in[8];
    const float* bn1_g    = (const float*)d_in[9];
    const float* bn1_b    = (const float*)d_in[10];
    const float* bn2_g    = (const float*)d_in[11];
    const float* bn2_b    = (const float*)d_in[12];
    const float* linW     = (const float*)d_in[13];
    const float* linb     = (const float*)d_in[14];
    const float* outW     = (const float*)d_in[15];
    const float* outb     = (const float*)d_in[16];
    float* out = (float*)d_out;

    float* ws    = (float*)d_ws;
    int*   topk  = (int*)(ws + 512);
    float* stats = ws + 10752;
    float* a_i   = ws + 11264;
    float* a_j   = ws + 44032;
    float* xw    = ws + 76800;
    float* gout  = ws + 2173952;

    k_p1   <<<1024, 256, 0, stream>>>(data, emb, Wg, att_i, att_j, att_em_i, att_em_j,
                                      topk, stats, a_i, a_j, xw);
    k_gnn2 <<<1024, 256, 0, stream>>>(xw, a_i, a_j, topk, bias, gout, stats);
    k_bn1  <<<1024, 256, 0, stream>>>(gout, emb, bn1_g, bn1_b, stats);
    k_head2<<<1024, 256, 0, stream>>>(gout, stats, bn2_g, bn2_b,
                                      linW, linb, outW, outb, out);
}

// Round 6
// 283.332 us; speedup vs baseline: 1.2333x; 1.2333x over previous
//
#include <hip/hip_runtime.h>
#include <math.h>

#define Bb 64
#define Nn 512
#define Ff 64
#define Dd 64
#define Kk 20
#define Hh 32
#define ROWS (Bb*Nn)   /* 32768 */
#define EPSc 1e-5f
#define NEG 0.2f

// workspace (float units):
// 512    : topk_idx[512*20] (int)
// 10752  : stats[512]: gsum1[64] gsq1[64] gsum2[64] gsq2[64]
// 11264  : a_i[32768]
// 44032  : a_j[32768]
// 76800  : xw[32768*64]
// 2173952: gout/y [32768*64]
// alpha[32768*20] lives in d_out (overwritten later by k_head2)

__device__ __forceinline__ float dot4(float4 a, float4 b) {
    return a.x*b.x + a.y*b.y + a.z*b.z + a.w*b.w;
}
__device__ __forceinline__ void xr4(float4& a, int m) {
    a.x += __shfl_xor(a.x, m); a.y += __shfl_xor(a.y, m);
    a.z += __shfl_xor(a.z, m); a.w += __shfl_xor(a.w, m);
}

// ---------- Launch 1: topk (blocks 0..511) || xw + a_i/a_j (blocks 512..1023)
__global__ __launch_bounds__(256) void k_p1(const float* __restrict__ data,
                                            const float* __restrict__ emb,
                                            const float* __restrict__ Wg,
                                            const float* __restrict__ att_i,
                                            const float* __restrict__ att_j,
                                            const float* __restrict__ att_em_i,
                                            const float* __restrict__ att_em_j,
                                            int* __restrict__ topk,
                                            float* __restrict__ stats,
                                            float* __restrict__ ai,
                                            float* __restrict__ aj,
                                            float* __restrict__ xw) {
    __shared__ __align__(16) float shbuf[576];
    int t = threadIdx.x, blk = blockIdx.x;
    if (blk < Nn) {
        float* wish = shbuf;
        float* sv   = shbuf + 64;
        int i = blk;
        if (t < 64) {
            float wv = emb[i*64 + t];
            float ss = wv*wv;
            #pragma unroll
            for (int s = 32; s > 0; s >>= 1) ss += __shfl_xor(ss, s);
            wish[t] = wv * (1.f / sqrtf(ss));
        }
        __syncthreads();
        int seg = t & 3, jl = t >> 2;
        const float4* wish4 = (const float4*)wish;
        float4 wn[4];
        #pragma unroll
        for (int q = 0; q < 4; q++) wn[q] = wish4[seg*4 + q];
        const float4* emb4 = (const float4*)emb;
        for (int jb = 0; jb < 8; jb++) {
            int j = jb*64 + jl;
            float p = 0.f, s2 = 0.f;
            #pragma unroll
            for (int q = 0; q < 4; q++) {
                float4 e = emb4[j*16 + seg*4 + q];
                p += dot4(e, wn[q]); s2 += dot4(e, e);
            }
            p  += __shfl_xor(p, 1);  p  += __shfl_xor(p, 2);
            s2 += __shfl_xor(s2, 1); s2 += __shfl_xor(s2, 2);
            if (seg == 0) sv[j] = p * (1.f / sqrtf(s2));
        }
        __syncthreads();
        if (t < 64) {
            float v[8];
            #pragma unroll
            for (int q = 0; q < 8; q++) v[q] = sv[q*64 + t];
            for (int k = 0; k < Kk; k++) {
                float bv = v[0]; int bi = t;
                #pragma unroll
                for (int q = 1; q < 8; q++)
                    if (v[q] > bv) { bv = v[q]; bi = q*64 + t; }
                #pragma unroll
                for (int s = 1; s < 64; s <<= 1) {
                    float ov = __shfl_xor(bv, s); int oi = __shfl_xor(bi, s);
                    if (ov > bv || (ov == bv && oi < bi)) { bv = ov; bi = oi; }
                }
                if (t == 0) topk[i*Kk + k] = bi;
                #pragma unroll
                for (int q = 0; q < 8; q++)
                    if (bi == q*64 + t) v[q] = -INFINITY;
            }
        }
    } else {
        if (blk == Nn) stats[t] = 0.f;               // zero BN accumulators
        float* sh = shbuf;
        int xcd = blk & 7, sub2 = (blk - Nn) >> 3;   // 0..63
        int d = t & 63, r = t >> 6;
        const float4* wg4 = (const float4*)Wg;
        float4 w4[16];
        #pragma unroll
        for (int q = 0; q < 16; q++) w4[q] = wg4[d*16 + q];
        float atti = att_i[d], attj = att_j[d];
        float aemi = att_em_i[d], aemj = att_em_j[d];
        const float4* sh4 = (const float4*)sh;
        for (int it = 0; it < 16; it++) {
            int g = xcd*1024 + it*64 + sub2;
            sh[t] = data[g*256 + t];
            __syncthreads();
            float acc = 0.f;
            #pragma unroll
            for (int q = 0; q < 16; q++) acc += dot4(sh4[r*16 + q], w4[q]);
            int row = g*4 + r;
            xw[row*64 + d] = acc;
            int n = row & (Nn - 1);
            float wv = emb[n*64 + d];
            float vi = acc*atti + wv*aemi;
            float vj = acc*attj + wv*aemj;
            #pragma unroll
            for (int s = 32; s > 0; s >>= 1) { vi += __shfl_xor(vi, s); vj += __shfl_xor(vj, s); }
            if (d == 0) { ai[row] = vi; aj[row] = vj; }
            __syncthreads();
        }
    }
}

// ---------- Launch 2: alpha[row][k] — one 32-lane half-wave per row, lanes = k
__global__ __launch_bounds__(256) void k_alpha(const float* __restrict__ ai,
                                               const float* __restrict__ aj,
                                               const int* __restrict__ topk,
                                               float* __restrict__ alpha) {
    int t = threadIdx.x;
    int hw = t >> 5;        // 0..7: half-wave within block
    int k  = t & 31;
    int row = blockIdx.x*8 + hw;
    int b = row >> 9, n = row & (Nn - 1);
    int base = b << 9;
    float aival = ai[row];
    float v = -1e30f;
    if (k < Kk) {
        int j = topk[n*Kk + k];
        float x = aival + aj[base + j];
        v = x > 0.f ? x : NEG * x;
    }
    float m = v;
    #pragma unroll
    for (int s = 1; s <= 16; s <<= 1) m = fmaxf(m, __shfl_xor(m, s));
    float e = (k < Kk) ? __expf(v - m) : 0.f;
    float es = e;
    #pragma unroll
    for (int s = 1; s <= 16; s <<= 1) es += __shfl_xor(es, s);
    if (k < Kk) alpha[row*Kk + k] = e / es;
}

// ---------- Launch 3: PV gather-accumulate (d-parallel, max ILP) + BN1 stats
__global__ __launch_bounds__(256) void k_pv(const float* __restrict__ xw,
                                            const float* __restrict__ alpha,
                                            const int* __restrict__ topk,
                                            const float* __restrict__ bias,
                                            float* __restrict__ gout,
                                            float* __restrict__ stats) {
    __shared__ float ssum[4][64], ssq[4][64];
    int t = threadIdx.x;
    int d = t & 63, r = t >> 6;
    int xcd = blockIdx.x & 7, sub = blockIdx.x >> 3;
    const int4*   topk4  = (const int4*)topk;     // 5 int4 per n (80B, 16B-aligned)
    const float4* alpha4 = (const float4*)alpha;  // 5 float4 per row
    float bias_d = bias[d];
    float lsum = 0.f, lsq = 0.f;
    for (int it = 0; it < 8; it++) {
        int g = xcd*1024 + it*128 + sub;
        int row = g*4 + r;
        int b = row >> 9, n = row & (Nn - 1);
        int base = b << 9;
        float acc = bias_d;
        #pragma unroll
        for (int c = 0; c < 5; c++) {
            int4   jj = topk4[n*5 + c];
            float4 aa = alpha4[row*5 + c];
            acc += aa.x * xw[(base + jj.x)*64 + d];
            acc += aa.y * xw[(base + jj.y)*64 + d];
            acc += aa.z * xw[(base + jj.z)*64 + d];
            acc += aa.w * xw[(base + jj.w)*64 + d];
        }
        gout[row*64 + d] = acc;
        lsum += acc; lsq += acc*acc;
    }
    ssum[r][d] = lsum; ssq[r][d] = lsq;
    __syncthreads();
    if (t < 64) {
        float s1 = ssum[0][t] + ssum[1][t] + ssum[2][t] + ssum[3][t];
        float s2 = ssq[0][t] + ssq[1][t] + ssq[2][t] + ssq[3][t];
        atomicAdd(&stats[t], s1);
        atomicAdd(&stats[64 + t], s2);
    }
}

// ---------- Launch 4: BN1 finalize (inline) + relu + *emb, BN2 stats
__global__ __launch_bounds__(256) void k_bn1(float* __restrict__ gout,
                                             const float* __restrict__ emb,
                                             const float* __restrict__ bn1_g,
                                             const float* __restrict__ bn1_b,
                                             float* __restrict__ stats) {
    __shared__ __align__(16) float4 s1[4][16], s2[4][16];
    int t = threadIdx.x;
    int xcd = blockIdx.x & 7, sub = blockIdx.x >> 3;
    int q = t & 15;
    float4 A4, C4;
    {
        float* Ap = &A4.x; float* Cp = &C4.x;
        #pragma unroll
        for (int c = 0; c < 4; c++) {
            int d = 4*q + c;
            float mean = stats[d] * (1.f/ROWS);
            float ex2  = stats[64+d] * (1.f/ROWS);
            float var  = ex2 - mean*mean;
            float A = (1.f / sqrtf(var + EPSc)) * bn1_g[d];
            Ap[c] = A; Cp[c] = bn1_b[d] - mean * A;
        }
    }
    float4* gout4 = (float4*)gout;
    const float4* emb4 = (const float4*)emb;
    float4 sum4 = {0,0,0,0}, sq4 = {0,0,0,0};
    #pragma unroll
    for (int i = 0; i < 2; i++) {
        int f = xcd*65536 + i*32768 + sub*256 + t;
        int row = f >> 4, n = row & (Nn - 1);
        float4 x = gout4[f];
        float4 wv = emb4[n*16 + q];
        float4 v;
        v.x = fmaxf(x.x*A4.x + C4.x, 0.f) * wv.x;
        v.y = fmaxf(x.y*A4.y + C4.y, 0.f) * wv.y;
        v.z = fmaxf(x.z*A4.z + C4.z, 0.f) * wv.z;
        v.w = fmaxf(x.w*A4.w + C4.w, 0.f) * wv.w;
        gout4[f] = v;
        sum4.x += v.x; sum4.y += v.y; sum4.z += v.z; sum4.w += v.w;
        sq4.x += v.x*v.x; sq4.y += v.y*v.y; sq4.z += v.z*v.z; sq4.w += v.w*v.w;
    }
    xr4(sum4, 16); xr4(sum4, 32);
    xr4(sq4, 16);  xr4(sq4, 32);
    int l = t & 63, w = t >> 6;
    if (l < 16) { s1[w][q] = sum4; s2[w][q] = sq4; }
    __syncthreads();
    if (t < 16) {
        float4 a = s1[0][t], c = s2[0][t];
        #pragma unroll
        for (int ww = 1; ww < 4; ww++) {
            float4 x1 = s1[ww][t], x2 = s2[ww][t];
            a.x += x1.x; a.y += x1.y; a.z += x1.z; a.w += x1.w;
            c.x += x2.x; c.y += x2.y; c.z += x2.z; c.w += x2.w;
        }
        atomicAdd(&stats[128+4*t+0], a.x); atomicAdd(&stats[128+4*t+1], a.y);
        atomicAdd(&stats[128+4*t+2], a.z); atomicAdd(&stats[128+4*t+3], a.w);
        atomicAdd(&stats[192+4*t+0], c.x); atomicAdd(&stats[192+4*t+1], c.y);
        atomicAdd(&stats[192+4*t+2], c.z); atomicAdd(&stats[192+4*t+3], c.w);
    }
}

// ---------- Launch 5: BN2 finalize (inline) + relu + lin(64->32) + out(32->64)
__global__ __launch_bounds__(256) void k_head2(const float* __restrict__ y,
                                               const float* __restrict__ stats,
                                               const float* __restrict__ bn2_g,
                                               const float* __restrict__ bn2_b,
                                               const float* __restrict__ linW,
                                               const float* __restrict__ linb,
                                               const float* __restrict__ outW,
                                               const float* __restrict__ outb,
                                               float* __restrict__ out) {
    __shared__ __align__(16) float zsh[4][64];
    __shared__ __align__(16) float hsh[4][32];
    int t = threadIdx.x;
    int d = t & 63, r = t >> 6;
    int j = d & 31, half = d >> 5;
    float mean = stats[128+d] * (1.f/ROWS);
    float ex2  = stats[192+d] * (1.f/ROWS);
    float var  = ex2 - mean*mean;
    float A = (1.f / sqrtf(var + EPSc)) * bn2_g[d];
    float C = bn2_b[d] - mean * A;
    const float4* linW4 = (const float4*)linW;
    const float4* outW4 = (const float4*)outW;
    float4 lw4[8], ow4[8];
    #pragma unroll
    for (int q = 0; q < 8; q++) lw4[q] = linW4[j*16 + half*8 + q];
    #pragma unroll
    for (int q = 0; q < 8; q++) ow4[q] = outW4[d*8 + q];
    float lb = linb[j], ob = outb[d];
    const float4* zsh4 = (const float4*)zsh;
    const float4* hsh4 = (const float4*)hsh;
    int xcd = blockIdx.x & 7, sub = blockIdx.x >> 3;
    for (int it = 0; it < 8; it++) {
        int g = xcd*1024 + it*128 + sub;
        int row = g*4 + r;
        float x = y[row*64 + d];
        float z = fmaxf(x*A + C, 0.f);
        zsh[r][d] = z;
        __syncthreads();
        float p = 0.f;
        #pragma unroll
        for (int q = 0; q < 8; q++) p += dot4(zsh4[r*16 + half*8 + q], lw4[q]);
        p += __shfl_xor(p, 32);
        if (half == 0) hsh[r][j] = p + lb;
        __syncthreads();
        float o = ob;
        #pragma unroll
        for (int q = 0; q < 8; q++) o += dot4(hsh4[r*8 + q], ow4[q]);
        out[row*64 + d] = o;
        __syncthreads();
    }
}

extern "C" void kernel_launch(void* const* d_in, const int* in_sizes, int n_in,
                              void* d_out, int out_size, void* d_ws, size_t ws_size,
                              hipStream_t stream) {
    const float* data     = (const float*)d_in[0];
    const float* emb      = (const float*)d_in[2];
    const float* Wg       = (const float*)d_in[3];
    const float* att_i    = (const float*)d_in[4];
    const float* att_j    = (const float*)d_in[5];
    const float* att_em_i = (const float*)d_in[6];
    const float* att_em_j = (const float*)d_in[7];
    const float* bias     = (const float*)d_in[8];
    const float* bn1_g    = (const float*)d_in[9];
    const float* bn1_b    = (const float*)d_in[10];
    const float* bn2_g    = (const float*)d_in[11];
    const float* bn2_b    = (const float*)d_in[12];
    const float* linW     = (const float*)d_in[13];
    const float* linb     = (const float*)d_in[14];
    const float* outW     = (const float*)d_in[15];
    const float* outb     = (const float*)d_in[16];
    float* out = (float*)d_out;

    float* ws    = (float*)d_ws;
    int*   topk  = (int*)(ws + 512);
    float* stats = ws + 10752;
    float* a_i   = ws + 11264;
    float* a_j   = ws + 44032;
    float* xw    = ws + 76800;
    float* gout  = ws + 2173952;
    float* alpha = out;            // d_out as scratch; overwritten by k_head2

    k_p1   <<<1024, 256, 0, stream>>>(data, emb, Wg, att_i, att_j, att_em_i, att_em_j,
                                      topk, stats, a_i, a_j, xw);
    k_alpha<<<ROWS/8, 256, 0, stream>>>(a_i, a_j, topk, alpha);
    k_pv   <<<1024, 256, 0, stream>>>(xw, alpha, topk, bias, gout, stats);
    k_bn1  <<<1024, 256, 0, stream>>>(gout, emb, bn1_g, bn1_b, stats);
    k_head2<<<1024, 256, 0, stream>>>(gout, stats, bn2_g, bn2_b,
                                      linW, linb, outW, outb, out);
}

// Round 7
// 239.135 us; speedup vs baseline: 1.4613x; 1.1848x over previous
//
#include <hip/hip_runtime.h>
#include <math.h>

#define Bb 64
#define Nn 512
#define Ff 64
#define Dd 64
#define Kk 20
#define Hh 32
#define ROWS (Bb*Nn)   /* 32768 */
#define EPSc 1e-5f
#define NEG 0.2f

// ws layout (float units):
//   512    : topk_idx[512*20] (int)
//   10752  : AC1[128] (A1[64],C1[64]) ; 10880: AC2[128]
//   11264  : a_i[32768]
//   44032  : a_j[32768]
//   76800  : xw[32768*64]
//   2173952: gout/y [32768*64]
// d_out scratch (2097152 floats, all dead before k_head2's final write):
//   0      : alpha[32768*20]
//   786432 : part1[2048*128]
//   1048576: part2[2048*128]

__device__ __forceinline__ float dot4(float4 a, float4 b) {
    return a.x*b.x + a.y*b.y + a.z*b.z + a.w*b.w;
}
__device__ __forceinline__ void xr4(float4& a, int m) {
    a.x += __shfl_xor(a.x, m); a.y += __shfl_xor(a.y, m);
    a.z += __shfl_xor(a.z, m); a.w += __shfl_xor(a.w, m);
}

// ---------- L1: topk (blocks 0..511) || xw + a_i/a_j (blocks 512..1023)
__global__ __launch_bounds__(256) void k_p1(const float* __restrict__ data,
                                            const float* __restrict__ emb,
                                            const float* __restrict__ Wg,
                                            const float* __restrict__ att_i,
                                            const float* __restrict__ att_j,
                                            const float* __restrict__ att_em_i,
                                            const float* __restrict__ att_em_j,
                                            int* __restrict__ topk,
                                            float* __restrict__ ai,
                                            float* __restrict__ aj,
                                            float* __restrict__ xw) {
    __shared__ __align__(16) float shbuf[576];
    int t = threadIdx.x, blk = blockIdx.x;
    if (blk < Nn) {
        float* wish = shbuf;
        float* sv   = shbuf + 64;
        int i = blk;
        if (t < 64) {
            float wv = emb[i*64 + t];
            float ss = wv*wv;
            #pragma unroll
            for (int s = 32; s > 0; s >>= 1) ss += __shfl_xor(ss, s);
            wish[t] = wv * (1.f / sqrtf(ss));
        }
        __syncthreads();
        int seg = t & 3, jl = t >> 2;
        const float4* wish4 = (const float4*)wish;
        float4 wn[4];
        #pragma unroll
        for (int q = 0; q < 4; q++) wn[q] = wish4[seg*4 + q];
        const float4* emb4 = (const float4*)emb;
        for (int jb = 0; jb < 8; jb++) {
            int j = jb*64 + jl;
            float p = 0.f, s2 = 0.f;
            #pragma unroll
            for (int q = 0; q < 4; q++) {
                float4 e = emb4[j*16 + seg*4 + q];
                p += dot4(e, wn[q]); s2 += dot4(e, e);
            }
            p  += __shfl_xor(p, 1);  p  += __shfl_xor(p, 2);
            s2 += __shfl_xor(s2, 1); s2 += __shfl_xor(s2, 2);
            if (seg == 0) sv[j] = p * (1.f / sqrtf(s2));
        }
        __syncthreads();
        if (t < 64) {
            float v[8];
            #pragma unroll
            for (int q = 0; q < 8; q++) v[q] = sv[q*64 + t];
            for (int k = 0; k < Kk; k++) {
                float bv = v[0]; int bi = t;
                #pragma unroll
                for (int q = 1; q < 8; q++)
                    if (v[q] > bv) { bv = v[q]; bi = q*64 + t; }
                #pragma unroll
                for (int s = 1; s < 64; s <<= 1) {
                    float ov = __shfl_xor(bv, s); int oi = __shfl_xor(bi, s);
                    if (ov > bv || (ov == bv && oi < bi)) { bv = ov; bi = oi; }
                }
                if (t == 0) topk[i*Kk + k] = bi;
                #pragma unroll
                for (int q = 0; q < 8; q++)
                    if (bi == q*64 + t) v[q] = -INFINITY;
            }
        }
    } else {
        float* sh = shbuf;
        int d = t & 63, r = t >> 6;
        const float4* wg4 = (const float4*)Wg;
        float4 w4[16];
        #pragma unroll
        for (int q = 0; q < 16; q++) w4[q] = wg4[d*16 + q];
        float atti = att_i[d], attj = att_j[d];
        float aemi = att_em_i[d], aemj = att_em_j[d];
        const float4* sh4 = (const float4*)sh;
        for (int it = 0; it < 16; it++) {
            int g = (blk - Nn)*16 + it;          // linear: contiguous rows per block
            sh[t] = data[g*256 + t];
            __syncthreads();
            float acc = 0.f;
            #pragma unroll
            for (int q = 0; q < 16; q++) acc += dot4(sh4[r*16 + q], w4[q]);
            int row = g*4 + r;
            xw[row*64 + d] = acc;
            int n = row & (Nn - 1);
            float wv = emb[n*64 + d];
            float vi = acc*atti + wv*aemi;
            float vj = acc*attj + wv*aemj;
            #pragma unroll
            for (int s = 32; s > 0; s >>= 1) { vi += __shfl_xor(vi, s); vj += __shfl_xor(vj, s); }
            if (d == 0) { ai[row] = vi; aj[row] = vj; }
            __syncthreads();
        }
    }
}

// ---------- L2: alpha[row][k] — one 32-lane half-wave per row, lanes = k
__global__ __launch_bounds__(256) void k_alpha(const float* __restrict__ ai,
                                               const float* __restrict__ aj,
                                               const int* __restrict__ topk,
                                               float* __restrict__ alpha) {
    int t = threadIdx.x;
    int hw = t >> 5, k = t & 31;
    int row = blockIdx.x*8 + hw;
    int b = row >> 9, n = row & (Nn - 1);
    int base = b << 9;
    float aival = ai[row];
    float v = -1e30f;
    if (k < Kk) {
        int j = topk[n*Kk + k];
        float x = aival + aj[base + j];
        v = x > 0.f ? x : NEG * x;
    }
    float m = v;
    #pragma unroll
    for (int s = 1; s <= 16; s <<= 1) m = fmaxf(m, __shfl_xor(m, s));
    float e = (k < Kk) ? __expf(v - m) : 0.f;
    float es = e;
    #pragma unroll
    for (int s = 1; s <= 16; s <<= 1) es += __shfl_xor(es, s);
    if (k < Kk) alpha[row*Kk + k] = e / es;
}

// ---------- L3: PV gather-accumulate (d-parallel) + per-block BN1 partials
__global__ __launch_bounds__(256) void k_pv(const float* __restrict__ xw,
                                            const float* __restrict__ alpha,
                                            const int* __restrict__ topk,
                                            const float* __restrict__ bias,
                                            float* __restrict__ gout,
                                            float* __restrict__ part1) {
    __shared__ float ssum[4][64], ssq[4][64];
    int t = threadIdx.x;
    int d = t & 63, r = t >> 6;
    const int4*   topk4  = (const int4*)topk;
    const float4* alpha4 = (const float4*)alpha;
    float bias_d = bias[d];
    float lsum = 0.f, lsq = 0.f;
    #pragma unroll
    for (int it = 0; it < 4; it++) {
        int row = blockIdx.x*16 + it*4 + r;
        int n = row & (Nn - 1);
        int base = row & ~(Nn - 1);
        float acc = bias_d;
        #pragma unroll
        for (int c = 0; c < 5; c++) {
            int4   jj = topk4[n*5 + c];
            float4 aa = alpha4[row*5 + c];
            acc += aa.x * xw[(base + jj.x)*64 + d];
            acc += aa.y * xw[(base + jj.y)*64 + d];
            acc += aa.z * xw[(base + jj.z)*64 + d];
            acc += aa.w * xw[(base + jj.w)*64 + d];
        }
        gout[row*64 + d] = acc;
        lsum += acc; lsq += acc*acc;
    }
    ssum[r][d] = lsum; ssq[r][d] = lsq;
    __syncthreads();
    if (t < 64) {
        float s1 = ssum[0][t] + ssum[1][t] + ssum[2][t] + ssum[3][t];
        float s2 = ssq[0][t] + ssq[1][t] + ssq[2][t] + ssq[3][t];
        part1[blockIdx.x*128 + t]      = s1;    // plain stores, no contention
        part1[blockIdx.x*128 + 64 + t] = s2;
    }
}

// ---------- reducer: partials -> A[64],C[64]  (1 block, 1024 threads)
__global__ __launch_bounds__(1024) void k_red(const float* __restrict__ part, int nb,
                                              const float* __restrict__ g,
                                              const float* __restrict__ bta,
                                              float* __restrict__ AC) {
    __shared__ float sh1[16][64], sh2[16][64];
    int t = threadIdx.x, d = t & 63, qt = t >> 6;
    float s1 = 0.f, s2 = 0.f;
    for (int b = qt; b < nb; b += 16) {
        s1 += part[b*128 + d];
        s2 += part[b*128 + 64 + d];
    }
    sh1[qt][d] = s1; sh2[qt][d] = s2;
    __syncthreads();
    if (t < 64) {
        float t1 = 0.f, t2 = 0.f;
        #pragma unroll
        for (int i = 0; i < 16; i++) { t1 += sh1[i][t]; t2 += sh2[i][t]; }
        float mean = t1 * (1.f/ROWS);
        float var  = t2 * (1.f/ROWS) - mean*mean;
        float A = (1.f / sqrtf(var + EPSc)) * g[t];
        AC[t]      = A;
        AC[64 + t] = bta[t] - mean * A;
    }
}

// ---------- L4: bn1 apply + relu + *emb (1 float4/thread) + BN2 partials
__global__ __launch_bounds__(256) void k_bn1(float* __restrict__ gout,
                                             const float* __restrict__ emb,
                                             const float* __restrict__ AC1,
                                             float* __restrict__ part2) {
    __shared__ __align__(16) float4 s1[4][16], s2[4][16];
    int t = threadIdx.x, q = t & 15;
    float4 A4 = ((const float4*)AC1)[q];
    float4 C4 = ((const float4*)AC1)[16 + q];
    int f = blockIdx.x*256 + t;
    int row = f >> 4, n = row & (Nn - 1);
    float4 x = ((float4*)gout)[f];
    float4 wv = ((const float4*)emb)[n*16 + q];
    float4 v;
    v.x = fmaxf(x.x*A4.x + C4.x, 0.f) * wv.x;
    v.y = fmaxf(x.y*A4.y + C4.y, 0.f) * wv.y;
    v.z = fmaxf(x.z*A4.z + C4.z, 0.f) * wv.z;
    v.w = fmaxf(x.w*A4.w + C4.w, 0.f) * wv.w;
    ((float4*)gout)[f] = v;
    float4 sum4 = v;
    float4 sq4; sq4.x = v.x*v.x; sq4.y = v.y*v.y; sq4.z = v.z*v.z; sq4.w = v.w*v.w;
    xr4(sum4, 16); xr4(sum4, 32);
    xr4(sq4, 16);  xr4(sq4, 32);
    int l = t & 63, w = t >> 6;
    if (l < 16) { s1[w][q] = sum4; s2[w][q] = sq4; }
    __syncthreads();
    if (t < 16) {
        float4 a = s1[0][t], c = s2[0][t];
        #pragma unroll
        for (int ww = 1; ww < 4; ww++) {
            float4 x1 = s1[ww][t], x2 = s2[ww][t];
            a.x += x1.x; a.y += x1.y; a.z += x1.z; a.w += x1.w;
            c.x += x2.x; c.y += x2.y; c.z += x2.z; c.w += x2.w;
        }
        ((float4*)part2)[blockIdx.x*32 + t]      = a;
        ((float4*)part2)[blockIdx.x*32 + 16 + t] = c;
    }
}

// ---------- L5: bn2 apply + relu + lin(64->32) + out(32->64)
__global__ __launch_bounds__(256) void k_head2(const float* __restrict__ y,
                                               const float* __restrict__ AC2,
                                               const float* __restrict__ linW,
                                               const float* __restrict__ linb,
                                               const float* __restrict__ outW,
                                               const float* __restrict__ outb,
                                               float* __restrict__ out) {
    __shared__ __align__(16) float zsh[4][64];
    __shared__ __align__(16) float hsh[4][32];
    int t = threadIdx.x;
    int d = t & 63, r = t >> 6;
    int j = d & 31, half = d >> 5;
    float A = AC2[d], C = AC2[64 + d];
    const float4* linW4 = (const float4*)linW;
    const float4* outW4 = (const float4*)outW;
    float4 lw4[8], ow4[8];
    #pragma unroll
    for (int q = 0; q < 8; q++) lw4[q] = linW4[j*16 + half*8 + q];
    #pragma unroll
    for (int q = 0; q < 8; q++) ow4[q] = outW4[d*8 + q];
    float lb = linb[j], ob = outb[d];
    const float4* zsh4 = (const float4*)zsh;
    const float4* hsh4 = (const float4*)hsh;
    #pragma unroll
    for (int it = 0; it < 4; it++) {
        int row = blockIdx.x*16 + it*4 + r;
        float x = y[row*64 + d];
        float z = fmaxf(x*A + C, 0.f);
        zsh[r][d] = z;
        __syncthreads();
        float p = 0.f;
        #pragma unroll
        for (int q = 0; q < 8; q++) p += dot4(zsh4[r*16 + half*8 + q], lw4[q]);
        p += __shfl_xor(p, 32);
        if (half == 0) hsh[r][j] = p + lb;
        __syncthreads();
        float o = ob;
        #pragma unroll
        for (int q = 0; q < 8; q++) o += dot4(hsh4[r*8 + q], ow4[q]);
        out[row*64 + d] = o;
        __syncthreads();
    }
}

extern "C" void kernel_launch(void* const* d_in, const int* in_sizes, int n_in,
                              void* d_out, int out_size, void* d_ws, size_t ws_size,
                              hipStream_t stream) {
    const float* data     = (const float*)d_in[0];
    const float* emb      = (const float*)d_in[2];
    const float* Wg       = (const float*)d_in[3];
    const float* att_i    = (const float*)d_in[4];
    const float* att_j    = (const float*)d_in[5];
    const float* att_em_i = (const float*)d_in[6];
    const float* att_em_j = (const float*)d_in[7];
    const float* bias     = (const float*)d_in[8];
    const float* bn1_g    = (const float*)d_in[9];
    const float* bn1_b    = (const float*)d_in[10];
    const float* bn2_g    = (const float*)d_in[11];
    const float* bn2_b    = (const float*)d_in[12];
    const float* linW     = (const float*)d_in[13];
    const float* linb     = (const float*)d_in[14];
    const float* outW     = (const float*)d_in[15];
    const float* outb     = (const float*)d_in[16];
    float* out = (float*)d_out;

    float* ws    = (float*)d_ws;
    int*   topk  = (int*)(ws + 512);
    float* AC1   = ws + 10752;
    float* AC2   = ws + 10880;
    float* a_i   = ws + 11264;
    float* a_j   = ws + 44032;
    float* xw    = ws + 76800;
    float* gout  = ws + 2173952;
    float* alpha = out;             // d_out scratch
    float* part1 = out + 786432;    // d_out scratch
    float* part2 = out + 1048576;   // d_out scratch

    k_p1   <<<1024, 256, 0, stream>>>(data, emb, Wg, att_i, att_j, att_em_i, att_em_j,
                                      topk, a_i, a_j, xw);
    k_alpha<<<ROWS/8, 256, 0, stream>>>(a_i, a_j, topk, alpha);
    k_pv   <<<2048, 256, 0, stream>>>(xw, alpha, topk, bias, gout, part1);
    k_red  <<<1, 1024, 0, stream>>>(part1, 2048, bn1_g, bn1_b, AC1);
    k_bn1  <<<2048, 256, 0, stream>>>(gout, emb, AC1, part2);
    k_red  <<<1, 1024, 0, stream>>>(part2, 2048, bn2_g, bn2_b, AC2);
    k_head2<<<2048, 256, 0, stream>>>(gout, AC2, linW, linb, outW, outb, out);
}

// Round 8
// 187.780 us; speedup vs baseline: 1.8609x; 1.2735x over previous
//
#include <hip/hip_runtime.h>
#include <math.h>

#define Bb 64
#define Nn 512
#define Ff 64
#define Dd 64
#define Kk 20
#define Hh 32
#define ROWS (Bb*Nn)   /* 32768 */
#define EPSc 1e-5f
#define NEG 0.2f

// ws layout (float units):
//   512    : topk_idx[512*20] (int)
//   10752  : AC1[128] ; 10880: AC2[128]
//   11264  : a_i[32768]
//   44032  : a_j[32768]
//   76800  : xw[32768*64]
//   2173952: gout/y [32768*64]
// d_out scratch (dead until k_head2's final write):
//   0      : alpha[32768*20]
//   786432 : part1[512*128]
//   1048576: part2[512*128]

__device__ __forceinline__ float dot4(float4 a, float4 b) {
    return a.x*b.x + a.y*b.y + a.z*b.z + a.w*b.w;
}
__device__ __forceinline__ void xr4(float4& a, int m) {
    a.x += __shfl_xor(a.x, m); a.y += __shfl_xor(a.y, m);
    a.z += __shfl_xor(a.z, m); a.w += __shfl_xor(a.w, m);
}

// ---------- L1: topk (blocks 0..511) || xw + a_i/a_j (blocks 512..1023)
__global__ __launch_bounds__(256) void k_p1(const float* __restrict__ data,
                                            const float* __restrict__ emb,
                                            const float* __restrict__ Wg,
                                            const float* __restrict__ att_i,
                                            const float* __restrict__ att_j,
                                            const float* __restrict__ att_em_i,
                                            const float* __restrict__ att_em_j,
                                            int* __restrict__ topk,
                                            float* __restrict__ ai,
                                            float* __restrict__ aj,
                                            float* __restrict__ xw) {
    __shared__ __align__(16) float shbuf[576];
    int t = threadIdx.x, blk = blockIdx.x;
    if (blk < Nn) {
        float* wish = shbuf;
        float* sv   = shbuf + 64;
        int i = blk;
        if (t < 64) {
            float wv = emb[i*64 + t];
            float ss = wv*wv;
            #pragma unroll
            for (int s = 32; s > 0; s >>= 1) ss += __shfl_xor(ss, s);
            wish[t] = wv * (1.f / sqrtf(ss));
        }
        __syncthreads();
        int seg = t & 3, jl = t >> 2;
        const float4* wish4 = (const float4*)wish;
        float4 wn[4];
        #pragma unroll
        for (int q = 0; q < 4; q++) wn[q] = wish4[seg*4 + q];
        const float4* emb4 = (const float4*)emb;
        for (int jb = 0; jb < 8; jb++) {
            int j = jb*64 + jl;
            float p = 0.f, s2 = 0.f;
            #pragma unroll
            for (int q = 0; q < 4; q++) {
                float4 e = emb4[j*16 + seg*4 + q];
                p += dot4(e, wn[q]); s2 += dot4(e, e);
            }
            p  += __shfl_xor(p, 1);  p  += __shfl_xor(p, 2);
            s2 += __shfl_xor(s2, 1); s2 += __shfl_xor(s2, 2);
            if (seg == 0) sv[j] = p * (1.f / sqrtf(s2));
        }
        __syncthreads();
        if (t < 64) {
            float v[8];
            #pragma unroll
            for (int q = 0; q < 8; q++) v[q] = sv[q*64 + t];
            for (int k = 0; k < Kk; k++) {
                float bv = v[0]; int bi = t;
                #pragma unroll
                for (int q = 1; q < 8; q++)
                    if (v[q] > bv) { bv = v[q]; bi = q*64 + t; }
                #pragma unroll
                for (int s = 1; s < 64; s <<= 1) {
                    float ov = __shfl_xor(bv, s); int oi = __shfl_xor(bi, s);
                    if (ov > bv || (ov == bv && oi < bi)) { bv = ov; bi = oi; }
                }
                if (t == 0) topk[i*Kk + k] = bi;
                #pragma unroll
                for (int q = 0; q < 8; q++)
                    if (bi == q*64 + t) v[q] = -INFINITY;
            }
        }
    } else {
        float* sh = shbuf;
        int d = t & 63, r = t >> 6;
        const float4* wg4 = (const float4*)Wg;
        float4 w4[16];
        #pragma unroll
        for (int q = 0; q < 16; q++) w4[q] = wg4[d*16 + q];
        float atti = att_i[d], attj = att_j[d];
        float aemi = att_em_i[d], aemj = att_em_j[d];
        const float4* sh4 = (const float4*)sh;
        for (int it = 0; it < 16; it++) {
            int g = (blk - Nn)*16 + it;
            // wave-local LDS exchange: wave r writes sh[64r..64r+63], reads only that
            sh[t] = data[g*256 + t];
            float acc = 0.f;
            #pragma unroll
            for (int q = 0; q < 16; q++) acc += dot4(sh4[r*16 + q], w4[q]);
            int row = g*4 + r;
            xw[row*64 + d] = acc;
            int n = row & (Nn - 1);
            float wv = emb[n*64 + d];
            float vi = acc*atti + wv*aemi;
            float vj = acc*attj + wv*aemj;
            #pragma unroll
            for (int s = 32; s > 0; s >>= 1) { vi += __shfl_xor(vi, s); vj += __shfl_xor(vj, s); }
            if (d == 0) { ai[row] = vi; aj[row] = vj; }
        }
    }
}

// ---------- L2: alpha[row][k] — one 32-lane half-wave per row, lanes = k
__global__ __launch_bounds__(256) void k_alpha(const float* __restrict__ ai,
                                               const float* __restrict__ aj,
                                               const int* __restrict__ topk,
                                               float* __restrict__ alpha) {
    int t = threadIdx.x;
    int hw = t >> 5, k = t & 31;
    int row = blockIdx.x*8 + hw;
    int b = row >> 9, n = row & (Nn - 1);
    int base = b << 9;
    float aival = ai[row];
    float v = -1e30f;
    if (k < Kk) {
        int j = topk[n*Kk + k];
        float x = aival + aj[base + j];
        v = x > 0.f ? x : NEG * x;
    }
    float m = v;
    #pragma unroll
    for (int s = 1; s <= 16; s <<= 1) m = fmaxf(m, __shfl_xor(m, s));
    float e = (k < Kk) ? __expf(v - m) : 0.f;
    float es = e;
    #pragma unroll
    for (int s = 1; s <= 16; s <<= 1) es += __shfl_xor(es, s);
    if (k < Kk) alpha[row*Kk + k] = e / es;
}

// ---------- L3: PV gather-accumulate (d-parallel) + per-block BN1 partials
__global__ __launch_bounds__(256) void k_pv(const float* __restrict__ xw,
                                            const float* __restrict__ alpha,
                                            const int* __restrict__ topk,
                                            const float* __restrict__ bias,
                                            float* __restrict__ gout,
                                            float* __restrict__ part1) {
    __shared__ float ssum[4][64], ssq[4][64];
    int t = threadIdx.x;
    int d = t & 63, r = t >> 6;
    const int4*   topk4  = (const int4*)topk;
    const float4* alpha4 = (const float4*)alpha;
    float bias_d = bias[d];
    float lsum = 0.f, lsq = 0.f;
    #pragma unroll 4
    for (int it = 0; it < 16; it++) {
        int row = blockIdx.x*64 + it*4 + r;
        int n = row & (Nn - 1);
        int base = row & ~(Nn - 1);
        float acc = bias_d;
        #pragma unroll
        for (int c = 0; c < 5; c++) {
            int4   jj = topk4[n*5 + c];
            float4 aa = alpha4[row*5 + c];
            acc += aa.x * xw[(base + jj.x)*64 + d];
            acc += aa.y * xw[(base + jj.y)*64 + d];
            acc += aa.z * xw[(base + jj.z)*64 + d];
            acc += aa.w * xw[(base + jj.w)*64 + d];
        }
        gout[row*64 + d] = acc;
        lsum += acc; lsq += acc*acc;
    }
    ssum[r][d] = lsum; ssq[r][d] = lsq;
    __syncthreads();
    if (t < 64) {
        float s1 = ssum[0][t] + ssum[1][t] + ssum[2][t] + ssum[3][t];
        float s2 = ssq[0][t] + ssq[1][t] + ssq[2][t] + ssq[3][t];
        part1[blockIdx.x*128 + t]      = s1;
        part1[blockIdx.x*128 + 64 + t] = s2;
    }
}

// ---------- reducer: partials[nb][128] -> A[64],C[64]  (1 block, 1024 threads)
__global__ __launch_bounds__(1024) void k_red(const float* __restrict__ part, int nb,
                                              const float* __restrict__ g,
                                              const float* __restrict__ bta,
                                              float* __restrict__ AC) {
    __shared__ float sh1[16][64], sh2[16][64];
    int t = threadIdx.x, d = t & 63, qt = t >> 6;
    float s1 = 0.f, s2 = 0.f;
    for (int b = qt; b < nb; b += 16) {
        s1 += part[b*128 + d];
        s2 += part[b*128 + 64 + d];
    }
    sh1[qt][d] = s1; sh2[qt][d] = s2;
    __syncthreads();
    if (t < 64) {
        float t1 = 0.f, t2 = 0.f;
        #pragma unroll
        for (int i = 0; i < 16; i++) { t1 += sh1[i][t]; t2 += sh2[i][t]; }
        float mean = t1 * (1.f/ROWS);
        float var  = t2 * (1.f/ROWS) - mean*mean;
        float A = (1.f / sqrtf(var + EPSc)) * g[t];
        AC[t]      = A;
        AC[64 + t] = bta[t] - mean * A;
    }
}

// ---------- L4: bn1 apply + relu + *emb (4 float4/thread) + BN2 partials
__global__ __launch_bounds__(256) void k_bn1(float* __restrict__ gout,
                                             const float* __restrict__ emb,
                                             const float* __restrict__ AC1,
                                             float* __restrict__ part2) {
    __shared__ __align__(16) float4 s1[4][16], s2[4][16];
    int t = threadIdx.x, q = t & 15;
    float4 A4 = ((const float4*)AC1)[q];
    float4 C4 = ((const float4*)AC1)[16 + q];
    float4 sum4 = {0,0,0,0}, sq4 = {0,0,0,0};
    #pragma unroll
    for (int i = 0; i < 4; i++) {
        int f = blockIdx.x*1024 + i*256 + t;
        int row = f >> 4, n = row & (Nn - 1);
        float4 x = ((float4*)gout)[f];
        float4 wv = ((const float4*)emb)[n*16 + q];
        float4 v;
        v.x = fmaxf(x.x*A4.x + C4.x, 0.f) * wv.x;
        v.y = fmaxf(x.y*A4.y + C4.y, 0.f) * wv.y;
        v.z = fmaxf(x.z*A4.z + C4.z, 0.f) * wv.z;
        v.w = fmaxf(x.w*A4.w + C4.w, 0.f) * wv.w;
        ((float4*)gout)[f] = v;
        sum4.x += v.x; sum4.y += v.y; sum4.z += v.z; sum4.w += v.w;
        sq4.x += v.x*v.x; sq4.y += v.y*v.y; sq4.z += v.z*v.z; sq4.w += v.w*v.w;
    }
    xr4(sum4, 16); xr4(sum4, 32);
    xr4(sq4, 16);  xr4(sq4, 32);
    int l = t & 63, w = t >> 6;
    if (l < 16) { s1[w][q] = sum4; s2[w][q] = sq4; }
    __syncthreads();
    if (t < 16) {
        float4 a = s1[0][t], c = s2[0][t];
        #pragma unroll
        for (int ww = 1; ww < 4; ww++) {
            float4 x1 = s1[ww][t], x2 = s2[ww][t];
            a.x += x1.x; a.y += x1.y; a.z += x1.z; a.w += x1.w;
            c.x += x2.x; c.y += x2.y; c.z += x2.z; c.w += x2.w;
        }
        ((float4*)part2)[blockIdx.x*32 + t]      = a;
        ((float4*)part2)[blockIdx.x*32 + 16 + t] = c;
    }
}

// ---------- L5: bn2 apply + relu + lin(64->32) + out(32->64), barrier-free
__global__ __launch_bounds__(256) void k_head2(const float* __restrict__ y,
                                               const float* __restrict__ AC2,
                                               const float* __restrict__ linW,
                                               const float* __restrict__ linb,
                                               const float* __restrict__ outW,
                                               const float* __restrict__ outb,
                                               float* __restrict__ out) {
    __shared__ __align__(16) float zsh[4][64];
    __shared__ __align__(16) float hsh[4][32];
    int t = threadIdx.x;
    int d = t & 63, r = t >> 6;
    int j = d & 31, half = d >> 5;
    float A = AC2[d], C = AC2[64 + d];
    const float4* linW4 = (const float4*)linW;
    const float4* outW4 = (const float4*)outW;
    float4 lw4[8], ow4[8];
    #pragma unroll
    for (int q = 0; q < 8; q++) lw4[q] = linW4[j*16 + half*8 + q];
    #pragma unroll
    for (int q = 0; q < 8; q++) ow4[q] = outW4[d*8 + q];
    float lb = linb[j], ob = outb[d];
    const float4* zsh4 = (const float4*)zsh;
    const float4* hsh4 = (const float4*)hsh;
    for (int it = 0; it < 16; it++) {
        int row = blockIdx.x*64 + it*4 + r;
        float x = y[row*64 + d];
        float z = fmaxf(x*A + C, 0.f);
        // wave-local LDS: wave r writes/reads only zsh[r]/hsh[r] — no barriers
        zsh[r][d] = z;
        float p = 0.f;
        #pragma unroll
        for (int q = 0; q < 8; q++) p += dot4(zsh4[r*16 + half*8 + q], lw4[q]);
        p += __shfl_xor(p, 32);
        if (half == 0) hsh[r][j] = p + lb;
        float o = ob;
        #pragma unroll
        for (int q = 0; q < 8; q++) o += dot4(hsh4[r*8 + q], ow4[q]);
        out[row*64 + d] = o;
    }
}

extern "C" void kernel_launch(void* const* d_in, const int* in_sizes, int n_in,
                              void* d_out, int out_size, void* d_ws, size_t ws_size,
                              hipStream_t stream) {
    const float* data     = (const float*)d_in[0];
    const float* emb      = (const float*)d_in[2];
    const float* Wg       = (const float*)d_in[3];
    const float* att_i    = (const float*)d_in[4];
    const float* att_j    = (const float*)d_in[5];
    const float* att_em_i = (const float*)d_in[6];
    const float* att_em_j = (const float*)d_in[7];
    const float* bias     = (const float*)d_in[8];
    const float* bn1_g    = (const float*)d_in[9];
    const float* bn1_b    = (const float*)d_in[10];
    const float* bn2_g    = (const float*)d_in[11];
    const float* bn2_b    = (const float*)d_in[12];
    const float* linW     = (const float*)d_in[13];
    const float* linb     = (const float*)d_in[14];
    const float* outW     = (const float*)d_in[15];
    const float* outb     = (const float*)d_in[16];
    float* out = (float*)d_out;

    float* ws    = (float*)d_ws;
    int*   topk  = (int*)(ws + 512);
    float* AC1   = ws + 10752;
    float* AC2   = ws + 10880;
    float* a_i   = ws + 11264;
    float* a_j   = ws + 44032;
    float* xw    = ws + 76800;
    float* gout  = ws + 2173952;
    float* alpha = out;             // d_out scratch
    float* part1 = out + 786432;    // d_out scratch
    float* part2 = out + 1048576;   // d_out scratch

    k_p1   <<<1024, 256, 0, stream>>>(data, emb, Wg, att_i, att_j, att_em_i, att_em_j,
                                      topk, a_i, a_j, xw);
    k_alpha<<<ROWS/8, 256, 0, stream>>>(a_i, a_j, topk, alpha);
    k_pv   <<<512, 256, 0, stream>>>(xw, alpha, topk, bias, gout, part1);
    k_red  <<<1, 1024, 0, stream>>>(part1, 512, bn1_g, bn1_b, AC1);
    k_bn1  <<<512, 256, 0, stream>>>(gout, emb, AC1, part2);
    k_red  <<<1, 1024, 0, stream>>>(part2, 512, bn2_g, bn2_b, AC2);
    k_head2<<<512, 256, 0, stream>>>(gout, AC2, linW, linb, outW, outb, out);
}